// Round 1
// baseline (868.327 us; speedup 1.0000x reference)
//
#include <hip/hip_runtime.h>
#include <stdint.h>

#define T_   16384
#define D_   1024
#define F_   4096
#define E_   8
#define CAP_ 2048

typedef __attribute__((ext_vector_type(8))) short bf16x8;
typedef __attribute__((ext_vector_type(4))) float f32x4;

__device__ __forceinline__ unsigned short f2bf(float f) {
  union { float f; uint32_t u; } v; v.f = f;
  uint32_t x = v.u;
  uint32_t r = (x + 0x7FFFu + ((x >> 16) & 1u)) >> 16;  // RTNE
  return (unsigned short)r;
}

__device__ __forceinline__ void gload_lds16(const void* g, void* l) {
  __builtin_amdgcn_global_load_lds(
      (const __attribute__((address_space(1))) void*)g,
      (__attribute__((address_space(3))) void*)l,
      16, 0, 0);
}

// ---------------- router: logits (fp64 acc), argmax, p_tok; emits bf16(x) ----
__global__ __launch_bounds__(256)
void router_kernel(const float* __restrict__ x, const float* __restrict__ Wr,
                   unsigned short* __restrict__ xb, int* __restrict__ eidx,
                   float* __restrict__ ptok)
{
  const int lane = threadIdx.x & 63;
  const int tok  = blockIdx.x * 4 + (threadIdx.x >> 6);
  const float* xr = x + (size_t)tok * D_;

  float xv[16];
  #pragma unroll
  for (int i = 0; i < 4; ++i) {
    const float4 v = *(const float4*)(xr + lane * 16 + i * 4);
    xv[i*4+0] = v.x; xv[i*4+1] = v.y; xv[i*4+2] = v.z; xv[i*4+3] = v.w;
  }

  double lg[8];
  #pragma unroll
  for (int e = 0; e < 8; ++e) lg[e] = 0.0;
  #pragma unroll
  for (int i = 0; i < 16; ++i) {
    const float* wr = Wr + (size_t)(lane * 16 + i) * E_;
    const double xd = (double)xv[i];
    #pragma unroll
    for (int e = 0; e < 8; ++e) lg[e] += xd * (double)wr[e];
  }
  #pragma unroll
  for (int off = 32; off >= 1; off >>= 1) {
    #pragma unroll
    for (int e = 0; e < 8; ++e) lg[e] += __shfl_xor(lg[e], off, 64);
  }

  unsigned short* xo = xb + (size_t)tok * D_ + lane * 16;
  #pragma unroll
  for (int i = 0; i < 4; ++i) {
    ushort4 o;
    o.x = f2bf(xv[i*4+0]); o.y = f2bf(xv[i*4+1]);
    o.z = f2bf(xv[i*4+2]); o.w = f2bf(xv[i*4+3]);
    *(ushort4*)(xo + i * 4) = o;
  }

  if (lane == 0) {
    int best = 0; double bv = lg[0];
    #pragma unroll
    for (int e = 1; e < 8; ++e) if (lg[e] > bv) { bv = lg[e]; best = e; }  // first-max tie-break
    double s = 0.0;
    #pragma unroll
    for (int e = 0; e < 8; ++e) s += exp(lg[e] - bv);
    eidx[tok] = best;
    ptok[tok] = (float)(1.0 / s);
  }
}

// ---------------- rank/dispatch: single block, token-order ranks -------------
__global__ __launch_bounds__(256)
void rank_kernel(const int* __restrict__ eidx, const float* __restrict__ ptok,
                 int* __restrict__ disp, float* __restrict__ scal)
{
  __shared__ int lcnt[E_][257];
  const int t = threadIdx.x;
  for (int i = t; i < E_ * CAP_; i += 256) { disp[i] = 0; scal[i] = 0.f; }

  int cnt[E_];
  #pragma unroll
  for (int e = 0; e < E_; ++e) cnt[e] = 0;
  const int base = t * (T_ / 256);
  for (int i = 0; i < T_ / 256; ++i) {
    const int ev = eidx[base + i];
    #pragma unroll
    for (int e = 0; e < E_; ++e) cnt[e] += (ev == e) ? 1 : 0;  // branchless, regs only
  }
  #pragma unroll
  for (int e = 0; e < E_; ++e) lcnt[e][t] = cnt[e];
  __syncthreads();
  if (t < E_) {                       // exclusive scan per expert
    int run = 0;
    for (int j = 0; j < 256; ++j) { const int c = lcnt[t][j]; lcnt[t][j] = run; run += c; }
  }
  __syncthreads();
  int rcur[E_];
  #pragma unroll
  for (int e = 0; e < E_; ++e) rcur[e] = lcnt[e][t];
  for (int i = 0; i < T_ / 256; ++i) {
    const int tokI = base + i;
    const int ev = eidx[tokI];
    int r = 0;
    #pragma unroll
    for (int e = 0; e < E_; ++e) { if (ev == e) { r = rcur[e]; rcur[e] = r + 1; } }
    if (r < CAP_) {
      const int s = ev * CAP_ + r;
      disp[s] = tokI;
      scal[s] = ptok[tokI];           // p >= 1/8 > 0 ⇒ scal==0 marks invalid slot
    }
  }
}

// ---------------- weight transpose + fp32->bf16: (R,C) -> (C,R) -------------
__global__ __launch_bounds__(256)
void transpose_w_kernel(const float* __restrict__ src, unsigned short* __restrict__ dst,
                        int R, int C)
{
  __shared__ float tile[64][68];
  const int e = blockIdx.y;
  const float* s = src + (size_t)e * R * C;
  unsigned short* d = dst + (size_t)e * R * C;
  const int nct = C >> 6;
  const int rt = blockIdx.x / nct, ct = blockIdx.x % nct;
  const int r0 = rt * 64, c0 = ct * 64;
  const int tr = threadIdx.x >> 4;
  const int tc = (threadIdx.x & 15) * 4;
  #pragma unroll
  for (int i = 0; i < 4; ++i) {
    const float4 v = *(const float4*)(s + (size_t)(r0 + tr + i*16) * C + (c0 + tc));
    tile[tr + i*16][tc+0] = v.x; tile[tr + i*16][tc+1] = v.y;
    tile[tr + i*16][tc+2] = v.z; tile[tr + i*16][tc+3] = v.w;
  }
  __syncthreads();
  #pragma unroll
  for (int i = 0; i < 4; ++i) {
    const int n = tr + i * 16;
    ushort4 o;
    o.x = f2bf(tile[tc+0][n]); o.y = f2bf(tile[tc+1][n]);
    o.z = f2bf(tile[tc+2][n]); o.w = f2bf(tile[tc+3][n]);
    *(ushort4*)(d + (size_t)(c0 + n) * R + (r0 + tc)) = o;
  }
}

// ---------------- grouped GEMM, 128x128 tile, BK=64, 4 waves -----------------
// EPI==0: h[slot] = relu(gather(xb) @ W1t) as bf16.  EPI==1: y[tok] = (h @ W2t) * p.
template<int EPI>
__global__ __launch_bounds__(256, 2)
void moe_gemm_kernel(const unsigned short* __restrict__ A0,
                     const unsigned short* __restrict__ Bt0,
                     unsigned short* __restrict__ H0,
                     float* __restrict__ Y,
                     const int* __restrict__ disp,
                     const float* __restrict__ scal,
                     int ebase, int N, int K)
{
  __shared__ __align__(16) unsigned short As[128 * 64];
  __shared__ __align__(16) unsigned short Bs[128 * 64];
  __shared__ uint32_t sRowOff[128];
  __shared__ float sScale[128];
  __shared__ int sTok[128];

  const int tid = threadIdx.x;
  const int Nt = N >> 7;
  const int MtNt = (CAP_ >> 7) * Nt;
  const int eloc = blockIdx.x / MtNt;
  const int rem  = blockIdx.x % MtNt;
  const int mt = rem / Nt, nt = rem % Nt;
  const int e = ebase + eloc;
  const int m0 = mt << 7, n0 = nt << 7;

  if (tid < 128) {
    const int slotAbs = e * CAP_ + m0 + tid;
    if (EPI == 0) {
      sRowOff[tid] = (uint32_t)disp[slotAbs] * (uint32_t)K;          // gather token rows
    } else {
      sRowOff[tid] = ((uint32_t)eloc * CAP_ + m0 + tid) * (uint32_t)K; // h rows direct
      sTok[tid]   = disp[slotAbs];
      sScale[tid] = scal[slotAbs];
    }
  }
  __syncthreads();

  size_t aOff[4], bOff[4];
  {
    const int rb  = tid >> 3;           // staging row base (0..31)
    const int c16 = (tid & 7) * 16;     // 16B chunk within 128B row
    const size_t ebOff = (size_t)eloc * (size_t)N * (size_t)K;
    #pragma unroll
    for (int i = 0; i < 4; ++i) {
      aOff[i] = (size_t)sRowOff[rb + i * 32] * 2 + c16;
      bOff[i] = (ebOff + (size_t)(n0 + i * 32 + rb) * (size_t)K) * 2 + c16;
    }
  }

  const int lane = tid & 63;
  const int wm = tid >> 7;        // wave row (0..1)
  const int wn = (tid >> 6) & 1;  // wave col (0..1)
  const int fr = lane & 15;
  const int fq = lane >> 4;

  f32x4 acc[4][4];
  #pragma unroll
  for (int a = 0; a < 4; ++a)
    #pragma unroll
    for (int b = 0; b < 4; ++b) acc[a][b] = (f32x4)(0.f);

  const char* Ab = (const char*)A0;
  const char* Bb = (const char*)Bt0;

  for (int k0 = 0; k0 < K; k0 += 64) {
    __syncthreads();                      // prev tile's reads done
    const size_t kByte = (size_t)k0 * 2;
    #pragma unroll
    for (int i = 0; i < 4; ++i)
      gload_lds16(Ab + aOff[i] + kByte, (char*)As + i * 4096 + tid * 16);
    #pragma unroll
    for (int i = 0; i < 4; ++i)
      gload_lds16(Bb + bOff[i] + kByte, (char*)Bs + i * 4096 + tid * 16);
    __syncthreads();                      // vmcnt(0) drain before compute
    #pragma unroll
    for (int kk = 0; kk < 64; kk += 32) {
      bf16x8 af[4], bfr[4];
      #pragma unroll
      for (int mi = 0; mi < 4; ++mi)
        af[mi] = *(const bf16x8*)(As + ((wm*64 + mi*16 + fr) * 64 + kk + fq*8));
      #pragma unroll
      for (int ni = 0; ni < 4; ++ni)
        bfr[ni] = *(const bf16x8*)(Bs + ((wn*64 + ni*16 + fr) * 64 + kk + fq*8));
      #pragma unroll
      for (int mi = 0; mi < 4; ++mi)
        #pragma unroll
        for (int ni = 0; ni < 4; ++ni)
          acc[mi][ni] = __builtin_amdgcn_mfma_f32_16x16x32_bf16(af[mi], bfr[ni], acc[mi][ni], 0, 0, 0);
    }
  }

  if (EPI == 0) {
    #pragma unroll
    for (int mi = 0; mi < 4; ++mi) {
      #pragma unroll
      for (int j = 0; j < 4; ++j) {
        const int row = wm*64 + mi*16 + fq*4 + j;     // C/D layout: col=lane&15, row=(lane>>4)*4+j
        unsigned short* hr = H0 + ((size_t)eloc * CAP_ + m0 + row) * (size_t)N + (n0 + wn*64 + fr);
        #pragma unroll
        for (int ni = 0; ni < 4; ++ni)
          hr[ni * 16] = f2bf(fmaxf(acc[mi][ni][j], 0.f));
      }
    }
  } else {
    #pragma unroll
    for (int mi = 0; mi < 4; ++mi) {
      #pragma unroll
      for (int j = 0; j < 4; ++j) {
        const int row = wm*64 + mi*16 + fq*4 + j;
        const float sc = sScale[row];
        if (sc > 0.f) {                                // invalid slots: no store
          float* yr = Y + (size_t)sTok[row] * (size_t)N + (n0 + wn*64 + fr);
          #pragma unroll
          for (int ni = 0; ni < 4; ++ni)
            yr[ni * 16] = acc[mi][ni][j] * sc;
        }
      }
    }
  }
}

// ---------------- host launch ------------------------------------------------
extern "C" void kernel_launch(void* const* d_in, const int* in_sizes, int n_in,
                              void* d_out, int out_size, void* d_ws, size_t ws_size,
                              hipStream_t stream)
{
  (void)in_sizes; (void)n_in; (void)out_size;
  const float* x  = (const float*)d_in[0];
  const float* Wr = (const float*)d_in[1];
  const float* W1 = (const float*)d_in[2];
  const float* W2 = (const float*)d_in[3];
  float* y = (float*)d_out;

  char* ws = (char*)d_ws;
  size_t off = 0;
  auto take = [&](size_t bytes) -> char* {
    char* p = ws + off;
    off += (bytes + 255) & ~(size_t)255;
    return p;
  };
  unsigned short* xb = (unsigned short*)take((size_t)T_ * D_ * 2);
  int*   eidx = (int*)  take((size_t)T_ * 4);
  float* ptok = (float*)take((size_t)T_ * 4);
  int*   disp = (int*)  take((size_t)T_ * 4);
  float* scal = (float*)take((size_t)T_ * 4);

  const size_t w1tB  = (size_t)E_ * D_ * F_ * 2;
  const size_t w2tB  = w1tB;
  const size_t hFull = (size_t)E_ * CAP_ * F_ * 2;
  const size_t hOne  = (size_t)CAP_ * F_ * 2;
  const size_t w1One = (size_t)D_ * F_ * 2;

  hipMemsetAsync(d_out, 0, (size_t)T_ * D_ * sizeof(float), stream);
  router_kernel<<<T_ / 4, 256, 0, stream>>>(x, Wr, xb, eidx, ptok);
  rank_kernel<<<1, 256, 0, stream>>>(eidx, ptok, disp, scal);

  const int Mt  = CAP_ / 128;
  const int Nt1 = F_ / 128, Nt2 = D_ / 128;
  const int tilesW = (D_ / 64) * (F_ / 64);

  if (off + w1tB + w2tB + hFull <= ws_size) {
    // tier A: everything resident, two big grouped-GEMM launches
    unsigned short* w1t = (unsigned short*)take(w1tB);
    unsigned short* w2t = (unsigned short*)take(w2tB);
    unsigned short* h   = (unsigned short*)take(hFull);
    transpose_w_kernel<<<dim3(tilesW, E_), 256, 0, stream>>>(W1, w1t, D_, F_);
    transpose_w_kernel<<<dim3(tilesW, E_), 256, 0, stream>>>(W2, w2t, F_, D_);
    moe_gemm_kernel<0><<<E_ * Mt * Nt1, 256, 0, stream>>>(xb, w1t, h, nullptr, disp, scal, 0, F_, D_);
    moe_gemm_kernel<1><<<E_ * Mt * Nt2, 256, 0, stream>>>(h, w2t, nullptr, y, disp, scal, 0, D_, F_);
  } else if (off + w1tB + w2tB + hOne <= ws_size) {
    // tier B: weights resident, per-expert h reuse
    unsigned short* w1t = (unsigned short*)take(w1tB);
    unsigned short* w2t = (unsigned short*)take(w2tB);
    unsigned short* h   = (unsigned short*)take(hOne);
    transpose_w_kernel<<<dim3(tilesW, E_), 256, 0, stream>>>(W1, w1t, D_, F_);
    transpose_w_kernel<<<dim3(tilesW, E_), 256, 0, stream>>>(W2, w2t, F_, D_);
    for (int e = 0; e < E_; ++e) {
      const size_t wOff = (size_t)e * D_ * F_;
      moe_gemm_kernel<0><<<Mt * Nt1, 256, 0, stream>>>(xb, w1t + wOff, h, nullptr, disp, scal, e, F_, D_);
      moe_gemm_kernel<1><<<Mt * Nt2, 256, 0, stream>>>(h, w2t + wOff, nullptr, y, disp, scal, e, D_, F_);
    }
  } else {
    // tier C: per-expert everything
    unsigned short* w1t = (unsigned short*)take(w1One);
    unsigned short* w2t = (unsigned short*)take(w1One);
    unsigned short* h   = (unsigned short*)take(hOne);
    for (int e = 0; e < E_; ++e) {
      const size_t wOff = (size_t)e * D_ * F_;
      transpose_w_kernel<<<dim3(tilesW, 1), 256, 0, stream>>>(W1 + wOff, w1t, D_, F_);
      transpose_w_kernel<<<dim3(tilesW, 1), 256, 0, stream>>>(W2 + wOff, w2t, F_, D_);
      moe_gemm_kernel<0><<<Mt * Nt1, 256, 0, stream>>>(xb, w1t, h, nullptr, disp, scal, e, F_, D_);
      moe_gemm_kernel<1><<<Mt * Nt2, 256, 0, stream>>>(h, w2t, nullptr, y, disp, scal, e, D_, F_);
    }
  }
}